// Round 2
// baseline (834.033 us; speedup 1.0000x reference)
//
#include <hip/hip_runtime.h>

// Problem constants
#define BB      16384
#define IN_DIM  256
#define NE      32
#define H1D     64
#define H2D     256
#define H3D     128
#define NOUT    128

typedef __bf16 bf16_t;
typedef __bf16 bf16x8  __attribute__((ext_vector_type(8)));
typedef float  f32x4   __attribute__((ext_vector_type(4)));

// ---- workspace layout (bytes) ----
#define OFF_XB  ((size_t)0)
#define OFF_W1  (OFF_XB + (size_t)BB*IN_DIM*2)          // xb: [B][256] bf16
#define OFF_W2  (OFF_W1 + (size_t)NE*H1D*IN_DIM*2)      // W1t: [E][64][256]
#define OFF_W3  (OFF_W2 + (size_t)NE*H2D*H1D*2)         // W2t: [E][256][64]
#define OFF_W4  (OFF_W3 + (size_t)NE*H3D*H2D*2)         // W3t: [E][128][256]
#define OFF_W5  (OFF_W4 + (size_t)NE*H1D*H3D*2)         // W4t: [E][64][128]
#define OFF_G   (OFF_W5 + (size_t)NE*NOUT*H1D*2)        // W5t: [E][128][64]
// g: [B][32] fp32 at OFF_G; total ~15 MB

// ---- prep: all 5 weight transposes in ONE kernel ----
// W [E][K][N] fp32 -> Wt [E][N][K] bf16, 64x64 LDS tiles.
// Per expert 20 tile-jobs: L1:4, L2:4, L3:8, L4:2, L5:2.
__global__ void cvt_w_all(const float* __restrict__ W1, const float* __restrict__ W2,
                          const float* __restrict__ W3, const float* __restrict__ W4,
                          const float* __restrict__ W5,
                          bf16_t* __restrict__ W1t, bf16_t* __restrict__ W2t,
                          bf16_t* __restrict__ W3t, bf16_t* __restrict__ W4t,
                          bf16_t* __restrict__ W5t)
{
    __shared__ float tile[64][65];
    const int j = blockIdx.x;
    const int e = j / 20;
    const int q = j % 20;
    const float* src; bf16_t* dst; int K, N, kt, nt;
    if (q < 4)       { K = 256; N = 64;  kt = q * 64;            nt = 0;            src = W1; dst = W1t; }
    else if (q < 8)  { K = 64;  N = 256; kt = 0;                 nt = (q - 4) * 64; src = W2; dst = W2t; }
    else if (q < 16) { K = 256; N = 128; int r = q - 8; kt = (r >> 1) * 64; nt = (r & 1) * 64; src = W3; dst = W3t; }
    else if (q < 18) { K = 128; N = 64;  kt = (q - 16) * 64;     nt = 0;            src = W4; dst = W4t; }
    else             { K = 64;  N = 128; kt = 0;                 nt = (q - 18) * 64; src = W5; dst = W5t; }
    src += (size_t)e * K * N;
    dst += (size_t)e * K * N;
    const int tx = threadIdx.x & 63;
    const int ty = threadIdx.x >> 6;
#pragma unroll
    for (int i = 0; i < 16; i++)
        tile[ty + i * 4][tx] = src[(size_t)(kt + ty + i * 4) * N + nt + tx];
    __syncthreads();
#pragma unroll
    for (int i = 0; i < 16; i++)
        dst[(size_t)(nt + ty + i * 4) * K + kt + tx] = (bf16_t)tile[tx][ty + i * 4];
}

// ---- gating: fp32 softmax(x @ Wg + bg), fused x->bf16 cast ----
__global__ void gating_kernel(const float* __restrict__ x, const float* __restrict__ Wg,
                              const float* __restrict__ bg, float* __restrict__ g,
                              bf16_t* __restrict__ xb)
{
    __shared__ float sx[8][256];
    const int tid  = threadIdx.x;
    const int row0 = blockIdx.x * 8;
    for (int s = tid; s < 512; s += 256) {
        const int off = s * 4;
        const int rr = off >> 8;
        const int cc = off & 255;
        *(float4*)&sx[rr][cc] = *(const float4*)(x + (size_t)(row0 + rr) * 256 + cc);
    }
    __syncthreads();
    // emit bf16 copy of the staged tile
    const float* sxf = &sx[0][0];
    for (int s = tid; s < 2048; s += 256)
        xb[(size_t)row0 * 256 + s] = (bf16_t)sxf[s];
    // gate
    const int wave = tid >> 6;
    const int lane = tid & 63;
    const int e    = lane & 31;
    const int rl   = wave * 2 + (lane >> 5);
    float acc = bg[e];
    const float* xr = sx[rl];
#pragma unroll 8
    for (int k = 0; k < 256; k++) acc = fmaf(xr[k], Wg[k * 32 + e], acc);
    float mx = acc;
#pragma unroll
    for (int off = 16; off > 0; off >>= 1) mx = fmaxf(mx, __shfl_xor(mx, off));
    const float ex = __expf(acc - mx);
    float sm = ex;
#pragma unroll
    for (int off = 16; off > 0; off >>= 1) sm += __shfl_xor(sm, off);
    g[(size_t)(row0 + rl) * 32 + e] = ex / sm;
}

// ---- one MFMA layer, balanced over all 8 waves ----
// wave w: m-tile = w>>1 (fixed), n-tiles = (w&1)*NH .. +NH-1, NH = N/32.
// A-frags either from regs (L1: x) or LDS src (stride SIN). Output relu -> dst (stride SOUT).
template<int K, int N, int SIN, int SOUT, bool A_REGS>
__device__ __forceinline__ void layer_fwd(const bf16x8* __restrict__ areg,
                                          const bf16_t* __restrict__ src, bf16_t* __restrict__ dst,
                                          const bf16_t* __restrict__ Wt, const float* __restrict__ bias,
                                          int lane16, int quad, int wave)
{
    constexpr int KS = K / 32;
    constexpr int NH = N / 32;                 // n-tiles per wave
    constexpr int CH = (NH > 4) ? 4 : NH;      // chunk to cap live accumulators
    const int m  = wave >> 1;
    const int n0 = (wave & 1) * NH;
    bf16x8 a[KS];
#pragma unroll
    for (int ks = 0; ks < KS; ks++)
        a[ks] = A_REGS ? areg[ks]
                       : *(const bf16x8*)(src + (m * 16 + lane16) * SIN + ks * 32 + quad * 8);
#pragma unroll
    for (int c = 0; c < NH; c += CH) {
        f32x4 acc[CH];
#pragma unroll
        for (int t = 0; t < CH; t++) acc[t] = (f32x4){0.f, 0.f, 0.f, 0.f};
#pragma unroll
        for (int t = 0; t < CH; t++) {
            const int n = (n0 + c + t) * 16 + lane16;
            const bf16_t* wp = Wt + (size_t)n * K + quad * 8;
#pragma unroll
            for (int ks = 0; ks < KS; ks++)
                acc[t] = __builtin_amdgcn_mfma_f32_16x16x32_bf16(a[ks], *(const bf16x8*)(wp + ks * 32),
                                                                 acc[t], 0, 0, 0);
        }
#pragma unroll
        for (int t = 0; t < CH; t++) {
            const int n = (n0 + c + t) * 16 + lane16;
            const float bv = bias[n];
#pragma unroll
            for (int r = 0; r < 4; r++) {
                float v = fmaxf(acc[t][r] + bv, 0.f);
                dst[(m * 16 + quad * 4 + r) * SOUT + n] = (bf16_t)v;
            }
        }
    }
}

// ---- main: 64-row tile x 16 experts per block; 2 expert-halves atomically combined ----
__global__ __launch_bounds__(512, 4) void moe_main(
    const bf16_t* __restrict__ xb,
    const bf16_t* __restrict__ W1t, const bf16_t* __restrict__ W2t,
    const bf16_t* __restrict__ W3t, const bf16_t* __restrict__ W4t,
    const bf16_t* __restrict__ W5t,
    const float* __restrict__ b1, const float* __restrict__ b2,
    const float* __restrict__ b3, const float* __restrict__ b4,
    const float* __restrict__ b5,
    const float* __restrict__ g, float* __restrict__ out)
{
    __shared__ bf16_t bufA[64 * 264];   // h2 (256 wide)
    __shared__ bf16_t bufB[64 * 136];   // h3 (128 wide)
    __shared__ bf16_t bufC[64 * 72];    // h1 / h4 (64 wide)
    __shared__ float  sG[64];

    const int tid    = threadIdx.x;
    const int wave   = tid >> 6;
    const int lane   = tid & 63;
    const int lane16 = lane & 15;
    const int quad   = lane >> 4;

    // XCD-aware decode: bit2 of blockIdx = expert half (XCDs 0-3 -> half 0, 4-7 -> half 1)
    const int gid  = blockIdx.x;
    const int eg   = (gid >> 2) & 1;
    const int tile = (gid >> 3) * 4 + (gid & 3);
    const int b0   = tile * 64;
    const int e0   = eg * 16;

    const int m = wave >> 1;            // this wave's m-tile, all layers

    // x A-fragments in registers: rows m*16+lane16, all 8 k-slices (reused 16 experts)
    bf16x8 xfrag[8];
    {
        const bf16_t* xp = xb + (size_t)(b0 + m * 16 + lane16) * IN_DIM + quad * 8;
#pragma unroll
        for (int ks = 0; ks < 8; ks++)
            xfrag[ks] = *(const bf16x8*)(xp + ks * 32);
    }

    float oacc[4][4];
#pragma unroll
    for (int t = 0; t < 4; t++)
#pragma unroll
        for (int r = 0; r < 4; r++) oacc[t][r] = 0.f;

    for (int e = e0; e < e0 + 16; e++) {
        if (tid < 64) sG[tid] = g[(size_t)(b0 + tid) * NE + e];

        // L1: x(regs) [64x256] @ [256x64] -> bufC
        layer_fwd<256, 64, 72, 72, true>(xfrag, nullptr, bufC,
                                         W1t + (size_t)e * (H1D * IN_DIM), b1 + e * H1D,
                                         lane16, quad, wave);
        __syncthreads();
        // L2: [64x64] @ [64x256] -> bufA
        layer_fwd<64, 256, 72, 264, false>(nullptr, bufC, bufA,
                                           W2t + (size_t)e * (H2D * H1D), b2 + e * H2D,
                                           lane16, quad, wave);
        __syncthreads();
        // L3: [64x256] @ [256x128] -> bufB
        layer_fwd<256, 128, 264, 136, false>(nullptr, bufA, bufB,
                                             W3t + (size_t)e * (H3D * H2D), b3 + e * H3D,
                                             lane16, quad, wave);
        __syncthreads();
        // L4: [64x128] @ [128x64] -> bufC
        layer_fwd<128, 64, 136, 72, false>(nullptr, bufB, bufC,
                                           W4t + (size_t)e * (H1D * H3D), b4 + e * H1D,
                                           lane16, quad, wave);
        __syncthreads();
        // L5: [64x64] @ [64x128], gated accumulate into oacc
        {
            const bf16_t* W5e = W5t + (size_t)e * (NOUT * H1D);
            const float*  b5e = b5 + e * NOUT;
            const int n0w = (wave & 1) * 4;
            bf16x8 a[2];
#pragma unroll
            for (int ks = 0; ks < 2; ks++)
                a[ks] = *(const bf16x8*)(bufC + (m * 16 + lane16) * 72 + ks * 32 + quad * 8);
#pragma unroll
            for (int t = 0; t < 4; t++) {
                const int n = (n0w + t) * 16 + lane16;
                f32x4 acc = (f32x4){0.f, 0.f, 0.f, 0.f};
#pragma unroll
                for (int ks = 0; ks < 2; ks++)
                    acc = __builtin_amdgcn_mfma_f32_16x16x32_bf16(
                        a[ks], *(const bf16x8*)(W5e + (size_t)n * H1D + ks * 32 + quad * 8), acc, 0, 0, 0);
                const float bv = b5e[n];
#pragma unroll
                for (int r = 0; r < 4; r++)
                    oacc[t][r] += sG[m * 16 + quad * 4 + r] * (acc[r] + bv);
            }
        }
        __syncthreads();
    }

    // combine the two expert-halves
    {
        const int n0w = (wave & 1) * 4;
#pragma unroll
        for (int t = 0; t < 4; t++)
#pragma unroll
            for (int r = 0; r < 4; r++)
                atomicAdd(out + (size_t)(b0 + m * 16 + quad * 4 + r) * NOUT + (n0w + t) * 16 + lane16,
                          oacc[t][r]);
    }
}

extern "C" void kernel_launch(void* const* d_in, const int* in_sizes, int n_in,
                              void* d_out, int out_size, void* d_ws, size_t ws_size,
                              hipStream_t stream)
{
    (void)in_sizes; (void)n_in; (void)ws_size;
    const float* x  = (const float*)d_in[0];
    const float* Wg = (const float*)d_in[1];
    const float* bg = (const float*)d_in[2];
    const float* W1 = (const float*)d_in[3];
    const float* b1 = (const float*)d_in[4];
    const float* W2 = (const float*)d_in[5];
    const float* b2 = (const float*)d_in[6];
    const float* W3 = (const float*)d_in[7];
    const float* b3 = (const float*)d_in[8];
    const float* W4 = (const float*)d_in[9];
    const float* b4 = (const float*)d_in[10];
    const float* W5 = (const float*)d_in[11];
    const float* b5 = (const float*)d_in[12];

    char* ws = (char*)d_ws;
    bf16_t* xb  = (bf16_t*)(ws + OFF_XB);
    bf16_t* W1t = (bf16_t*)(ws + OFF_W1);
    bf16_t* W2t = (bf16_t*)(ws + OFF_W2);
    bf16_t* W3t = (bf16_t*)(ws + OFF_W3);
    bf16_t* W4t = (bf16_t*)(ws + OFF_W4);
    bf16_t* W5t = (bf16_t*)(ws + OFF_W5);
    float*  g   = (float*)(ws + OFF_G);
    float*  out = (float*)d_out;

    hipMemsetAsync(d_out, 0, (size_t)out_size * sizeof(float), stream);
    cvt_w_all<<<dim3(NE * 20), dim3(256), 0, stream>>>(W1, W2, W3, W4, W5, W1t, W2t, W3t, W4t, W5t);
    gating_kernel<<<dim3(2048), dim3(256), 0, stream>>>(x, Wg, bg, g, xb);
    moe_main<<<dim3(512), dim3(512), 0, stream>>>(xb, W1t, W2t, W3t, W4t, W5t,
                                                  b1, b2, b3, b4, b5, g, out);
}

// Round 3
// 365.516 us; speedup vs baseline: 2.2818x; 2.2818x over previous
//
#include <hip/hip_runtime.h>

// Problem constants
#define BB      16384
#define IN_DIM  256
#define NE      32
#define H1D     64
#define H2D     256
#define H3D     128
#define NOUT    128

typedef __bf16 bf16_t;
typedef __bf16 bf16x8  __attribute__((ext_vector_type(8)));
typedef float  f32x4   __attribute__((ext_vector_type(4)));

// ---- workspace layout (bytes): bf16 transposed weights ----
#define OFF_W1  ((size_t)0)                              // W1t: [E][64][256]
#define OFF_W2  (OFF_W1 + (size_t)NE*H1D*IN_DIM*2)       // W2t: [E][256][64]
#define OFF_W3  (OFF_W2 + (size_t)NE*H2D*H1D*2)          // W3t: [E][128][256]
#define OFF_W4  (OFF_W3 + (size_t)NE*H3D*H2D*2)          // W4t: [E][64][128]
#define OFF_W5  (OFF_W4 + (size_t)NE*H1D*H3D*2)          // W5t: [E][128][64]
#define OFF_WG  (OFF_W5 + (size_t)NE*NOUT*H1D*2)         // Wgt: [32][256]

// ---- prep: all weight transposes (incl. Wg) in ONE kernel ----
// W [.][K][N] fp32 -> Wt [.][N][K] bf16 via 64x64 LDS tiles. 21 jobs per expert.
__global__ void cvt_w_all(const float* __restrict__ W1, const float* __restrict__ W2,
                          const float* __restrict__ W3, const float* __restrict__ W4,
                          const float* __restrict__ W5, const float* __restrict__ Wg,
                          bf16_t* __restrict__ W1t, bf16_t* __restrict__ W2t,
                          bf16_t* __restrict__ W3t, bf16_t* __restrict__ W4t,
                          bf16_t* __restrict__ W5t, bf16_t* __restrict__ Wgt)
{
    __shared__ float tile[64][65];
    const int j = blockIdx.x;
    const int e = j / 21;
    const int q = j % 21;
    const int tid = threadIdx.x;

    if (q == 20) {
        // Wg [256][32] -> Wgt [32][256]; only 4 of the 32 instances do work.
        if (e >= 4) return;
        const int kt = e * 64;
        const int tx = tid & 31, ty = tid >> 5;
#pragma unroll
        for (int i = 0; i < 8; i++)
            tile[ty + i * 8][tx] = Wg[(size_t)(kt + ty + i * 8) * 32 + tx];
        __syncthreads();
        const int tx2 = tid & 63, ty2 = tid >> 6;
#pragma unroll
        for (int i = 0; i < 8; i++)
            Wgt[(size_t)(ty2 + i * 4) * 256 + kt + tx2] = (bf16_t)tile[tx2][ty2 + i * 4];
        return;
    }

    const float* src; bf16_t* dst; int K, N, kt, nt;
    if (q < 4)       { K = 256; N = 64;  kt = q * 64;            nt = 0;             src = W1; dst = W1t; }
    else if (q < 8)  { K = 64;  N = 256; kt = 0;                 nt = (q - 4) * 64;  src = W2; dst = W2t; }
    else if (q < 16) { K = 256; N = 128; int r = q - 8; kt = (r >> 1) * 64; nt = (r & 1) * 64; src = W3; dst = W3t; }
    else if (q < 18) { K = 128; N = 64;  kt = (q - 16) * 64;     nt = 0;             src = W4; dst = W4t; }
    else             { K = 64;  N = 128; kt = 0;                 nt = (q - 18) * 64; src = W5; dst = W5t; }
    src += (size_t)e * K * N;
    dst += (size_t)e * K * N;
    const int tx = tid & 63;
    const int ty = tid >> 6;
#pragma unroll
    for (int i = 0; i < 16; i++)
        tile[ty + i * 4][tx] = src[(size_t)(kt + ty + i * 4) * N + nt + tx];
    __syncthreads();
#pragma unroll
    for (int i = 0; i < 16; i++)
        dst[(size_t)(nt + ty + i * 4) * K + kt + tx] = (bf16_t)tile[tx][ty + i * 4];
}

// ---- generic MFMA layer piece: MT m-tiles from m0, NT n-tiles from n0 ----
// src LDS [64][SIN] bf16; dst LDS [64][SOUT]; Wt global [N][K] bf16; relu+bias.
template<int K, int SIN, int SOUT, int MT, int NT>
__device__ __forceinline__ void layer_gen(const bf16_t* __restrict__ src, bf16_t* __restrict__ dst,
                                          const bf16_t* __restrict__ Wt, const float* __restrict__ bias,
                                          int m0, int n0, int lane16, int quad)
{
    constexpr int KS = K / 32;
    bf16x8 b[NT][KS];
#pragma unroll
    for (int nt = 0; nt < NT; nt++) {
        const bf16_t* wp = Wt + (size_t)((n0 + nt) * 16 + lane16) * K + quad * 8;
#pragma unroll
        for (int ks = 0; ks < KS; ks++) b[nt][ks] = *(const bf16x8*)(wp + ks * 32);
    }
#pragma unroll
    for (int m = 0; m < MT; m++) {
        bf16x8 a[KS];
        const bf16_t* ap = src + ((m0 + m) * 16 + lane16) * SIN + quad * 8;
#pragma unroll
        for (int ks = 0; ks < KS; ks++) a[ks] = *(const bf16x8*)(ap + ks * 32);
        f32x4 acc[NT];
#pragma unroll
        for (int nt = 0; nt < NT; nt++) acc[nt] = (f32x4){0.f, 0.f, 0.f, 0.f};
#pragma unroll
        for (int nt = 0; nt < NT; nt++)
#pragma unroll
            for (int ks = 0; ks < KS; ks++)
                acc[nt] = __builtin_amdgcn_mfma_f32_16x16x32_bf16(a[ks], b[nt][ks], acc[nt], 0, 0, 0);
#pragma unroll
        for (int nt = 0; nt < NT; nt++) {
            const int col = (n0 + nt) * 16 + lane16;
            const float bv = bias[col];
#pragma unroll
            for (int r = 0; r < 4; r++)
                dst[((m0 + m) * 16 + quad * 4 + r) * SOUT + col] =
                    (bf16_t)fmaxf(acc[nt][r] + bv, 0.f);
        }
    }
}

// ---- LDS carve (bytes) ----
#define L_SX   0                       // x tile   [64][264] bf16 = 33792
#define L_BA   33792                   // h2       [64][264] bf16 = 33792  (aliases gating logits)
#define L_BB   67584                   // h3       [64][136] bf16 = 17408
#define L_C1   84992                   // h1       [64][72]  bf16 = 9216
#define L_C2   94208                   // h4       [64][72]  bf16 = 9216
#define L_SG   103424                  // g        [32][64]  fp32 = 8192
#define L_TOT  111616

// ---- main: 64-row tile, in-kernel gating, all 32 experts, 4 barriers/expert ----
__global__ __launch_bounds__(512) void moe_main(
    const float* __restrict__ x,
    const bf16_t* __restrict__ W1t, const bf16_t* __restrict__ W2t,
    const bf16_t* __restrict__ W3t, const bf16_t* __restrict__ W4t,
    const bf16_t* __restrict__ W5t, const bf16_t* __restrict__ Wgt,
    const float* __restrict__ bg,
    const float* __restrict__ b1, const float* __restrict__ b2,
    const float* __restrict__ b3, const float* __restrict__ b4,
    const float* __restrict__ b5, float* __restrict__ out)
{
    __shared__ __align__(16) char lds[L_TOT];
    bf16_t* sX  = (bf16_t*)(lds + L_SX);
    bf16_t* bufA = (bf16_t*)(lds + L_BA);
    bf16_t* bufB = (bf16_t*)(lds + L_BB);
    bf16_t* bufC1 = (bf16_t*)(lds + L_C1);
    bf16_t* bufC2 = (bf16_t*)(lds + L_C2);
    float*  sLg = (float*)(lds + L_BA);   // [64][33] fp32, alias of bufA (gating only)
    float*  sG  = (float*)(lds + L_SG);   // [32][64] fp32

    const int tid    = threadIdx.x;
    const int wave   = tid >> 6;
    const int lane   = tid & 63;
    const int lane16 = lane & 15;
    const int quad   = lane >> 4;
    const int b0     = blockIdx.x * 64;

    // ---- stage x: fp32 -> bf16, 64x256 into sX (stride 264) ----
    {
        const int r  = tid >> 3;
        const int c0 = (tid & 7) * 32;
        const float* src = x + (size_t)(b0 + r) * IN_DIM + c0;
        bf16_t* dstp = sX + r * 264 + c0;
#pragma unroll
        for (int jj = 0; jj < 4; jj++) {
            const float4 v0 = *(const float4*)(src + jj * 8);
            const float4 v1 = *(const float4*)(src + jj * 8 + 4);
            bf16x8 o = { (bf16_t)v0.x, (bf16_t)v0.y, (bf16_t)v0.z, (bf16_t)v0.w,
                         (bf16_t)v1.x, (bf16_t)v1.y, (bf16_t)v1.z, (bf16_t)v1.w };
            *(bf16x8*)(dstp + jj * 8) = o;
        }
    }
    __syncthreads();

    // ---- gating: logits via MFMA -> sLg, softmax -> sG ----
    {
        const int m  = wave >> 1;
        const int nt = wave & 1;
        bf16x8 b[8], a[8];
        const bf16_t* wp = Wgt + (size_t)(nt * 16 + lane16) * 256 + quad * 8;
        const bf16_t* ap = sX + (m * 16 + lane16) * 264 + quad * 8;
#pragma unroll
        for (int ks = 0; ks < 8; ks++) { b[ks] = *(const bf16x8*)(wp + ks * 32);
                                         a[ks] = *(const bf16x8*)(ap + ks * 32); }
        f32x4 acc = (f32x4){0.f, 0.f, 0.f, 0.f};
#pragma unroll
        for (int ks = 0; ks < 8; ks++)
            acc = __builtin_amdgcn_mfma_f32_16x16x32_bf16(a[ks], b[ks], acc, 0, 0, 0);
        const int col = nt * 16 + lane16;
        const float bgv = bg[col];
#pragma unroll
        for (int r = 0; r < 4; r++)
            sLg[(m * 16 + quad * 4 + r) * 33 + col] = acc[r] + bgv;
    }
    __syncthreads();
    {
        const int row = tid >> 3;
        const int c0  = (tid & 7) * 4;
        float l[4];
#pragma unroll
        for (int jj = 0; jj < 4; jj++) l[jj] = sLg[row * 33 + c0 + jj];
        float mx = fmaxf(fmaxf(l[0], l[1]), fmaxf(l[2], l[3]));
#pragma unroll
        for (int off = 1; off < 8; off <<= 1) mx = fmaxf(mx, __shfl_xor(mx, off));
        float ex[4], sm = 0.f;
#pragma unroll
        for (int jj = 0; jj < 4; jj++) { ex[jj] = __expf(l[jj] - mx); sm += ex[jj]; }
#pragma unroll
        for (int off = 1; off < 8; off <<= 1) sm += __shfl_xor(sm, off);
        const float rs = 1.f / sm;
#pragma unroll
        for (int jj = 0; jj < 4; jj++) sG[(c0 + jj) * 64 + row] = ex[jj] * rs;
    }
    __syncthreads();

    float oacc[4][4];
#pragma unroll
    for (int m = 0; m < 4; m++)
#pragma unroll
        for (int r = 0; r < 4; r++) oacc[m][r] = 0.f;

    const int mpair = (wave >> 2) * 2;   // m-base for L1/L4
    const int nq    = wave & 3;          // n-tile for L1/L4
    const int l5col = wave * 16 + lane16;

    for (int e = 0; e < NE; e++) {
        // Phase A: L1(e) -> bufC1 ; merged L5(e-1): bufC2 -> oacc (gated)
        layer_gen<256, 264, 72, 2, 1>(sX, bufC1, W1t + (size_t)e * (H1D * IN_DIM),
                                      b1 + e * H1D, mpair, nq, lane16, quad);
        if (e > 0) {
            const int ep = e - 1;
            const bf16_t* W5e = W5t + (size_t)ep * (NOUT * H1D);
            bf16x8 b5f[2];
#pragma unroll
            for (int ks = 0; ks < 2; ks++)
                b5f[ks] = *(const bf16x8*)(W5e + (size_t)l5col * H1D + ks * 32 + quad * 8);
            const float bv = b5[ep * NOUT + l5col];
#pragma unroll
            for (int m = 0; m < 4; m++) {
                f32x4 acc = (f32x4){0.f, 0.f, 0.f, 0.f};
#pragma unroll
                for (int ks = 0; ks < 2; ks++) {
                    bf16x8 a = *(const bf16x8*)(bufC2 + (m * 16 + lane16) * 72 + ks * 32 + quad * 8);
                    acc = __builtin_amdgcn_mfma_f32_16x16x32_bf16(a, b5f[ks], acc, 0, 0, 0);
                }
#pragma unroll
                for (int r = 0; r < 4; r++)
                    oacc[m][r] += sG[ep * 64 + m * 16 + quad * 4 + r] * (acc[r] + bv);
            }
        }
        __syncthreads();
        // Phase B: L2: bufC1 [64x64] @ [64x256] -> bufA
        layer_gen<64, 72, 264, 4, 2>(bufC1, bufA, W2t + (size_t)e * (H2D * H1D),
                                     b2 + e * H2D, 0, wave * 2, lane16, quad);
        __syncthreads();
        // Phase C: L3: bufA [64x256] @ [256x128] -> bufB
        layer_gen<256, 264, 136, 4, 1>(bufA, bufB, W3t + (size_t)e * (H3D * H2D),
                                       b3 + e * H3D, 0, wave, lane16, quad);
        __syncthreads();
        // Phase D: L4: bufB [64x128] @ [128x64] -> bufC2
        layer_gen<128, 136, 72, 2, 1>(bufB, bufC2, W4t + (size_t)e * (H1D * H3D),
                                      b4 + e * H1D, mpair, nq, lane16, quad);
        __syncthreads();
    }

    // Final L5 for e=31
    {
        const int ep = NE - 1;
        const bf16_t* W5e = W5t + (size_t)ep * (NOUT * H1D);
        bf16x8 b5f[2];
#pragma unroll
        for (int ks = 0; ks < 2; ks++)
            b5f[ks] = *(const bf16x8*)(W5e + (size_t)l5col * H1D + ks * 32 + quad * 8);
        const float bv = b5[ep * NOUT + l5col];
#pragma unroll
        for (int m = 0; m < 4; m++) {
            f32x4 acc = (f32x4){0.f, 0.f, 0.f, 0.f};
#pragma unroll
            for (int ks = 0; ks < 2; ks++) {
                bf16x8 a = *(const bf16x8*)(bufC2 + (m * 16 + lane16) * 72 + ks * 32 + quad * 8);
                acc = __builtin_amdgcn_mfma_f32_16x16x32_bf16(a, b5f[ks], acc, 0, 0, 0);
            }
#pragma unroll
            for (int r = 0; r < 4; r++)
                oacc[m][r] += sG[ep * 64 + m * 16 + quad * 4 + r] * (acc[r] + bv);
        }
    }

    // Write out: wave owns n-tile `wave`, cols l5col; rows m*16+quad*4+r
#pragma unroll
    for (int m = 0; m < 4; m++)
#pragma unroll
        for (int r = 0; r < 4; r++)
            out[(size_t)(b0 + m * 16 + quad * 4 + r) * NOUT + l5col] = oacc[m][r];
}

extern "C" void kernel_launch(void* const* d_in, const int* in_sizes, int n_in,
                              void* d_out, int out_size, void* d_ws, size_t ws_size,
                              hipStream_t stream)
{
    (void)in_sizes; (void)n_in; (void)out_size; (void)ws_size;
    const float* x  = (const float*)d_in[0];
    const float* Wg = (const float*)d_in[1];
    const float* bg = (const float*)d_in[2];
    const float* W1 = (const float*)d_in[3];
    const float* b1 = (const float*)d_in[4];
    const float* W2 = (const float*)d_in[5];
    const float* b2 = (const float*)d_in[6];
    const float* W3 = (const float*)d_in[7];
    const float* b3 = (const float*)d_in[8];
    const float* W4 = (const float*)d_in[9];
    const float* b4 = (const float*)d_in[10];
    const float* W5 = (const float*)d_in[11];
    const float* b5 = (const float*)d_in[12];

    char* ws = (char*)d_ws;
    bf16_t* W1t = (bf16_t*)(ws + OFF_W1);
    bf16_t* W2t = (bf16_t*)(ws + OFF_W2);
    bf16_t* W3t = (bf16_t*)(ws + OFF_W3);
    bf16_t* W4t = (bf16_t*)(ws + OFF_W4);
    bf16_t* W5t = (bf16_t*)(ws + OFF_W5);
    bf16_t* Wgt = (bf16_t*)(ws + OFF_WG);
    float*  out = (float*)d_out;

    cvt_w_all<<<dim3(NE * 21), dim3(256), 0, stream>>>(W1, W2, W3, W4, W5, Wg,
                                                       W1t, W2t, W3t, W4t, W5t, Wgt);
    moe_main<<<dim3(256), dim3(512), 0, stream>>>(x, W1t, W2t, W3t, W4t, W5t, Wgt, bg,
                                                  b1, b2, b3, b4, b5, out);
}